// Round 13
// baseline (54.927 us; speedup 1.0000x reference)
//
#include <hip/hip_runtime.h>
#include <hip/hip_bf16.h>
#include <stdint.h>

#define NDIM 4096
#define CDIM 64
#define NSPLIT 8
#define SPAN (NDIM / NSPLIT)   // 512 keys per split
#define LOG2E 1.44269504088896f

typedef float f32x16 __attribute__((ext_vector_type(16)));
typedef short bf16x8 __attribute__((ext_vector_type(8)));
union U4B { uint4 u; bf16x8 b; };

// single-instruction packed f32->bf16 (RNE), lo -> bits[15:0], hi -> bits[31:16]
static __device__ __forceinline__ uint32_t cvtpk(float lo, float hi) {
  uint32_t r;
  asm("v_cvt_pk_bf16_f32 %0, %1, %2" : "=v"(r) : "v"(lo), "v"(hi));
  return r;
}
static __device__ __forceinline__ uint16_t f2bf(float f) {
  uint32_t r;
  asm("v_cvt_pk_bf16_f32 %0, %1, %1" : "=v"(r) : "v"(f));
  return (uint16_t)r;
}
static __device__ __forceinline__ float fexp2(float x) {
  return __builtin_amdgcn_exp2f(x);   // raw v_exp_f32
}

// ---------------- Kernel 1: projections via MFMA (fp32 -> bf16) -------------
// 512 blocks x 256 threads (4 waves). Block = (b, 32 columns); wave roles:
// w0: V rows 0-31, w1: V rows 32-63, w2: Q (from x_opt), w3: K (from x_sar).
// V written key-blocked vf2[b][kb=key/16][ch][kk=key%16]; K packed [n][8].
__global__ __launch_bounds__(256) void proj_kernel(
    const float* __restrict__ x_opt, const float* __restrict__ x_sar,
    const float* __restrict__ wq, const float* __restrict__ bq,
    const float* __restrict__ wk, const float* __restrict__ bk,
    const float* __restrict__ wvp, const float* __restrict__ bv,
    uint16_t* __restrict__ qf, uint16_t* __restrict__ kfp,
    uint16_t* __restrict__ vf2)
{
  const int tid = threadIdx.x;
  const int w = tid >> 6;       // wave role
  const int l = tid & 63;
  const int x = l & 31;
  const int hi = l >> 5;

  const int id = blockIdx.x;
  const int b = id >> 7;
  const int n0 = (id & 127) * 32;
  const size_t xbase = (size_t)b * CDIM * NDIM;

  // ---- X B-fragment (lane = col n0+x, regs = 8 k along kc*16 + 8hi + j)
  const float* xsrc = (w == 2) ? x_opt : x_sar;
  bf16x8 xB[4];
#pragma unroll
  for (int kc = 0; kc < 4; kc++) {
    float sv[8];
#pragma unroll
    for (int j = 0; j < 8; j++)
      sv[j] = xsrc[xbase + (size_t)(kc * 16 + hi * 8 + j) * NDIM + n0 + x];
    U4B us;
    us.u = make_uint4(cvtpk(sv[0], sv[1]), cvtpk(sv[2], sv[3]),
                      cvtpk(sv[4], sv[5]), cvtpk(sv[6], sv[7]));
    xB[kc] = us.b;
  }

  // ---- W A-fragment
  bf16x8 aF[4];
#pragma unroll
  for (int kc = 0; kc < 4; kc++) {
    U4B ua;
    ua.u = make_uint4(0u, 0u, 0u, 0u);
    if (w < 2) {
      const float* wr = wvp + (w * 32 + x) * 64 + kc * 16 + hi * 8;
      float4 wa = ((const float4*)wr)[0];
      float4 wb = ((const float4*)wr)[1];
      ua.u = make_uint4(cvtpk(wa.x, wa.y), cvtpk(wa.z, wa.w),
                        cvtpk(wb.x, wb.y), cvtpk(wb.z, wb.w));
    } else if (x < 8) {
      const float* wr = ((w == 2) ? wq : wk) + x * 64 + kc * 16 + hi * 8;
      float4 wa = ((const float4*)wr)[0];
      float4 wb = ((const float4*)wr)[1];
      ua.u = make_uint4(cvtpk(wa.x, wa.y), cvtpk(wa.z, wa.w),
                        cvtpk(wb.x, wb.y), cvtpk(wb.z, wb.w));
    }
    aF[kc] = ua.b;
  }

  const f32x16 z16 = {0.f,0.f,0.f,0.f, 0.f,0.f,0.f,0.f,
                      0.f,0.f,0.f,0.f, 0.f,0.f,0.f,0.f};
  f32x16 acc = z16;
#pragma unroll
  for (int kc = 0; kc < 4; kc++)
    acc = __builtin_amdgcn_mfma_f32_32x32x16_bf16(aF[kc], xB[kc], acc, 0, 0, 0);

  if (w < 2) {
    // V stores into blocked layout: kb = (n0+x)/16, kk = (n0+x)%16
    const size_t kbbase = (size_t)b * 256 + (n0 >> 4) + (x >> 4);
    const int kk = x & 15;
#pragma unroll
    for (int r = 0; r < 16; r++) {
      const int row = w * 32 + (r & 3) + 8 * (r >> 2) + 4 * hi;
      vf2[(kbbase * 64 + row) * 16 + kk] = f2bf(acc[r] + bv[row]);
    }
  } else if (w == 2) {
    // Q store: regs 0-3 hold d = 4hi + r; layout [n][16], zero upper 8
    float gv[4];
#pragma unroll
    for (int r = 0; r < 4; r++) gv[r] = (acc[r] + bq[4 * hi + r]) * LOG2E;
    const size_t nrow = ((size_t)b * NDIM + n0 + x) * 16;
    uint2 st;
    st.x = cvtpk(gv[0], gv[1]); st.y = cvtpk(gv[2], gv[3]);
    *(uint2*)(qf + nrow + hi * 4) = st;
    if (hi == 0) {
      const uint4 z4 = make_uint4(0u, 0u, 0u, 0u);
      *(uint4*)(qf + nrow + 8) = z4;
    }
  } else {
    // K store: packed [n][8] (real d only)
    float gv[4];
#pragma unroll
    for (int r = 0; r < 4; r++) gv[r] = acc[r] + bk[4 * hi + r];
    uint2 st;
    st.x = cvtpk(gv[0], gv[1]); st.y = cvtpk(gv[2], gv[3]);
    *(uint2*)(kfp + ((size_t)b * NDIM + n0 + x) * 8 + hi * 4) = st;
  }
}

// ------------- Kernel 2: flash attention partial (K-split) -----------
// 512 blocks x 256 threads, sp = id&7 pins KV span to one XCD's L2.
// 64 queries per wave (2 Q fragments): every K/V fragment load is shared
// by 2 QK + 8 PV MFMAs -> VMEM instructions and K/V traffic halved vs the
// 32q/wave version. NO LDS, NO barriers; 1-quarter register lookahead.
__global__ __launch_bounds__(256, 2) void attn_kernel(
    const uint16_t* __restrict__ qf, const uint16_t* __restrict__ kfp,
    const uint16_t* __restrict__ vf2,
    uint16_t* __restrict__ po, float* __restrict__ ls)
{
  const int tid = threadIdx.x;
  const int w = tid >> 6;
  const int l = tid & 63;
  const int x = l & 31;       // query col (S,O) / key row (K-frag) / channel (V-frag)
  const int hi = l >> 5;

  const int id = blockIdx.x;           // 512 = 8 sp x 16 qb x 4 b
  const int sp = id & 7;
  const int qb = (id >> 3) & 15;
  const int b = id >> 7;

  const int n0 = qb * 256;
  const int qrow0 = n0 + w * 64 + x;   // fragment 0 query; fragment 1 = +32

  U4B qfr0, qfr1;
  qfr0.u = *(const uint4*)(qf + ((size_t)b * NDIM + qrow0) * 16 + hi * 8);
  qfr1.u = *(const uint4*)(qf + ((size_t)b * NDIM + qrow0 + 32) * 16 + hi * 8);

  const uint32_t hmask = hi ? 0u : 0xFFFFFFFFu;   // zero k=8..15 half

  // per-lane bases; all loop offsets are compile-time immediates (u16 units)
  const uint16_t* kbase = kfp + ((size_t)b * NDIM + sp * SPAN + x) * 8;
  const uint16_t* vbase =
      vf2 + (((size_t)b * 256 + sp * 32) * 64 + x) * 16 + hi * 8;

  const f32x16 z16 = {0.f,0.f,0.f,0.f, 0.f,0.f,0.f,0.f,
                      0.f,0.f,0.f,0.f, 0.f,0.f,0.f,0.f};
  f32x16 oacc00 = z16, oacc01 = z16;   // frag0: ch 0-31, ch 32-63
  f32x16 oacc10 = z16, oacc11 = z16;   // frag1
  float lacc0[4] = {0.f, 0.f, 0.f, 0.f};
  float lacc1[4] = {0.f, 0.f, 0.f, 0.f};

  // prologue: quarter-0 K and V fragments
  uint4 kc   = *(const uint4*)(kbase);
  uint4 va00 = *(const uint4*)(vbase);           // sub0 ch 0-31
  uint4 va01 = *(const uint4*)(vbase + 512);     // sub0 ch 32-63
  uint4 va10 = *(const uint4*)(vbase + 1024);    // sub1 ch 0-31
  uint4 va11 = *(const uint4*)(vbase + 1536);    // sub1 ch 32-63

#pragma unroll
  for (int gq = 0; gq < 16; gq++) {
    // ---- prefetch quarter gq+1 (final iteration overruns into adjacent
    // ws region: allocated memory, value dead)
    const int vo = (gq + 1) * 2048;
    uint4 kn   = *(const uint4*)(kbase + (gq + 1) * 256);
    uint4 vn00 = *(const uint4*)(vbase + vo);
    uint4 vn01 = *(const uint4*)(vbase + vo + 512);
    uint4 vn10 = *(const uint4*)(vbase + vo + 1024);
    uint4 vn11 = *(const uint4*)(vbase + vo + 1536);

    // ---- scores S^T (32 keys x 2x32 queries), lane(q=x,hi):
    // key = (r&3) + 8*(r>>2) + 4hi
    U4B ka;
    ka.u.x = kc.x & hmask; ka.u.y = kc.y & hmask;
    ka.u.z = kc.z & hmask; ka.u.w = kc.w & hmask;
    f32x16 s0 = __builtin_amdgcn_mfma_f32_32x32x16_bf16(ka.b, qfr0.b, z16, 0, 0, 0);
    f32x16 s1 = __builtin_amdgcn_mfma_f32_32x32x16_bf16(ka.b, qfr1.b, z16, 0, 0, 0);

    // ---- fused p = exp2(s) -> bf16 pack -> row-sum
    uint32_t W0[8], W1[8];
#pragma unroll
    for (int j = 0; j < 8; j++) {
      const float a0 = fexp2(s0[2 * j]);
      const float a1 = fexp2(s0[2 * j + 1]);
      W0[j] = cvtpk(a0, a1);
      lacc0[j & 3] += a0 + a1;
      const float c0 = fexp2(s1[2 * j]);
      const float c1 = fexp2(s1[2 * j + 1]);
      W1[j] = cvtpk(c0, c1);
      lacc1[j & 3] += c0 + c1;
    }

    // ---- PV: O^T += V^T . P^T (2 sub-chunks; V frags shared by both frags)
    __builtin_amdgcn_s_setprio(1);
    {
      uint32_t a0 = W0[0], b0 = W0[2], a1 = W0[1], b1 = W0[3];
      uint32_t c0 = W1[0], d0 = W1[2], c1 = W1[1], d1 = W1[3];
      asm("v_permlane32_swap_b32 %0, %1" : "+v"(a0), "+v"(b0));
      asm("v_permlane32_swap_b32 %0, %1" : "+v"(a1), "+v"(b1));
      asm("v_permlane32_swap_b32 %0, %1" : "+v"(c0), "+v"(d0));
      asm("v_permlane32_swap_b32 %0, %1" : "+v"(c1), "+v"(d1));
      U4B pf0, pf1, va, vb;
      pf0.u = make_uint4(a0, a1, b0, b1);
      pf1.u = make_uint4(c0, c1, d0, d1);
      va.u = va00; vb.u = va01;
      oacc00 = __builtin_amdgcn_mfma_f32_32x32x16_bf16(va.b, pf0.b, oacc00, 0, 0, 0);
      oacc01 = __builtin_amdgcn_mfma_f32_32x32x16_bf16(vb.b, pf0.b, oacc01, 0, 0, 0);
      oacc10 = __builtin_amdgcn_mfma_f32_32x32x16_bf16(va.b, pf1.b, oacc10, 0, 0, 0);
      oacc11 = __builtin_amdgcn_mfma_f32_32x32x16_bf16(vb.b, pf1.b, oacc11, 0, 0, 0);
    }
    {
      uint32_t a0 = W0[4], b0 = W0[6], a1 = W0[5], b1 = W0[7];
      uint32_t c0 = W1[4], d0 = W1[6], c1 = W1[5], d1 = W1[7];
      asm("v_permlane32_swap_b32 %0, %1" : "+v"(a0), "+v"(b0));
      asm("v_permlane32_swap_b32 %0, %1" : "+v"(a1), "+v"(b1));
      asm("v_permlane32_swap_b32 %0, %1" : "+v"(c0), "+v"(d0));
      asm("v_permlane32_swap_b32 %0, %1" : "+v"(c1), "+v"(d1));
      U4B pf0, pf1, va, vb;
      pf0.u = make_uint4(a0, a1, b0, b1);
      pf1.u = make_uint4(c0, c1, d0, d1);
      va.u = va10; vb.u = va11;
      oacc00 = __builtin_amdgcn_mfma_f32_32x32x16_bf16(va.b, pf0.b, oacc00, 0, 0, 0);
      oacc01 = __builtin_amdgcn_mfma_f32_32x32x16_bf16(vb.b, pf0.b, oacc01, 0, 0, 0);
      oacc10 = __builtin_amdgcn_mfma_f32_32x32x16_bf16(va.b, pf1.b, oacc10, 0, 0, 0);
      oacc11 = __builtin_amdgcn_mfma_f32_32x32x16_bf16(vb.b, pf1.b, oacc11, 0, 0, 0);
    }
    __builtin_amdgcn_s_setprio(0);

    kc = kn; va00 = vn00; va01 = vn01; va10 = vn10; va11 = vn11;
  }

  // ---- epilogue: raw (unnormalized) partial O in bf16 + row-sums
#pragma unroll
  for (int f = 0; f < 2; f++) {
    const int qrow = qrow0 + f * 32;
    uint16_t* prow = po + (((size_t)sp * 4 + b) * NDIM + qrow) * CDIM;
#pragma unroll
    for (int cb = 0; cb < 2; cb++) {
      const f32x16 oa = (f == 0) ? (cb == 0 ? oacc00 : oacc01)
                                 : (cb == 0 ? oacc10 : oacc11);
#pragma unroll
      for (int u = 0; u < 4; u++) {
        uint2 st;
        st.x = cvtpk(oa[u * 4 + 0], oa[u * 4 + 1]);
        st.y = cvtpk(oa[u * 4 + 2], oa[u * 4 + 3]);
        *(uint2*)(prow + cb * 32 + u * 8 + hi * 4) = st;
      }
    }
    float ltot = (f == 0) ? (lacc0[0] + lacc0[1]) + (lacc0[2] + lacc0[3])
                          : (lacc1[0] + lacc1[1]) + (lacc1[2] + lacc1[3]);
    ltot += __shfl_xor(ltot, 32);
    if (hi == 0)
      ls[((size_t)sp * 4 + b) * NDIM + qrow] = ltot;
  }
}

// ---------------- Kernel 3: split merge + gamma*O + residual ----------------
// 512 blocks x 256 threads; block = (b, 32 queries); transpose via LDS.
// out = gamma * (sum_s po_s) / (sum_s l_s) + x_opt
__global__ __launch_bounds__(256) void merge_kernel(
    const uint16_t* __restrict__ po, const float* __restrict__ ls,
    const float* __restrict__ x_opt, const float* __restrict__ gamma,
    float* __restrict__ out)
{
  __shared__ float ot[32][65];
  const int tid = threadIdx.x;
  const int b = blockIdx.x >> 7;
  const int n0 = (blockIdx.x & 127) * 32;
  {
    const int q = tid >> 3;
    const int co = (tid & 7) * 8;
    const int nq = n0 + q;
    float wsum = 0.f;
    float acc[8] = {0.f, 0.f, 0.f, 0.f, 0.f, 0.f, 0.f, 0.f};
#pragma unroll
    for (int s = 0; s < NSPLIT; s++) {
      wsum += ls[((size_t)s * 4 + b) * NDIM + nq];
      const uint4 pv = *(const uint4*)(po + (((size_t)s * 4 + b) * NDIM + nq) * CDIM + co);
      const uint32_t* pw = (const uint32_t*)&pv;
#pragma unroll
      for (int j = 0; j < 4; j++) {
        acc[j * 2 + 0] += __uint_as_float(pw[j] << 16);
        acc[j * 2 + 1] += __uint_as_float(pw[j] & 0xFFFF0000u);
      }
    }
    const float inv = 1.f / wsum;
#pragma unroll
    for (int j = 0; j < 8; j++) ot[q][co + j] = acc[j] * inv;
  }
  __syncthreads();
  {
    const float gm = gamma[0];
    const int c = tid >> 2;
    const int j8 = (tid & 3) * 8;
    const float* xp = x_opt + ((size_t)b * CDIM + c) * NDIM + n0 + j8;
    float* op = out + ((size_t)b * CDIM + c) * NDIM + n0 + j8;
#pragma unroll
    for (int h = 0; h < 2; h++) {
      float4 xv = ((const float4*)xp)[h];
      float4 ov;
      ov.x = gm * ot[j8 + h * 4 + 0][c] + xv.x;
      ov.y = gm * ot[j8 + h * 4 + 1][c] + xv.y;
      ov.z = gm * ot[j8 + h * 4 + 2][c] + xv.z;
      ov.w = gm * ot[j8 + h * 4 + 3][c] + xv.w;
      ((float4*)op)[h] = ov;
    }
  }
}

extern "C" void kernel_launch(void* const* d_in, const int* in_sizes, int n_in,
                              void* d_out, int out_size, void* d_ws, size_t ws_size,
                              hipStream_t stream) {
  const float* x_opt = (const float*)d_in[0];
  const float* x_sar = (const float*)d_in[1];
  const float* wq    = (const float*)d_in[2];
  const float* bq    = (const float*)d_in[3];
  const float* wk    = (const float*)d_in[4];
  const float* bk    = (const float*)d_in[5];
  const float* wvp   = (const float*)d_in[6];
  const float* bv    = (const float*)d_in[7];
  const float* gamma = (const float*)d_in[8];
  float* outp = (float*)d_out;

  // ws: qf 512K | kfp 256K(+pad) | vf2 2M | po(bf16) 16M | ls 512K
  uint16_t* qf  = (uint16_t*)d_ws;
  uint16_t* kfp = (uint16_t*)((char*)d_ws + 524288);
  uint16_t* vf2 = (uint16_t*)((char*)d_ws + 1048576);
  uint16_t* po  = (uint16_t*)((char*)d_ws + 3145728);
  float* lsp    = (float*)((char*)d_ws + 19922944);

  proj_kernel<<<512, 256, 0, stream>>>(x_opt, x_sar, wq, bq, wk, bk, wvp, bv,
                                       qf, kfp, vf2);
  attn_kernel<<<512, 256, 0, stream>>>(qf, kfp, vf2, po, lsp);
  merge_kernel<<<512, 256, 0, stream>>>(po, lsp, x_opt, gamma, outp);
}

// Round 14
// 41.113 us; speedup vs baseline: 1.3360x; 1.3360x over previous
//
#include <hip/hip_runtime.h>
#include <hip/hip_bf16.h>
#include <stdint.h>

#define NDIM 4096
#define CDIM 64
#define NSPLIT 16
#define SPAN (NDIM / NSPLIT)   // 256 keys per split
#define NQ4 (SPAN / 32)        // 8 quarters per block
#define LOG2E 1.44269504088896f

typedef float f32x16 __attribute__((ext_vector_type(16)));
typedef short bf16x8 __attribute__((ext_vector_type(8)));
union U4B { uint4 u; bf16x8 b; };

// single-instruction packed f32->bf16 (RNE), lo -> bits[15:0], hi -> bits[31:16]
static __device__ __forceinline__ uint32_t cvtpk(float lo, float hi) {
  uint32_t r;
  asm("v_cvt_pk_bf16_f32 %0, %1, %2" : "=v"(r) : "v"(lo), "v"(hi));
  return r;
}
static __device__ __forceinline__ uint16_t f2bf(float f) {
  uint32_t r;
  asm("v_cvt_pk_bf16_f32 %0, %1, %1" : "=v"(r) : "v"(f));
  return (uint16_t)r;
}
static __device__ __forceinline__ float fexp2(float x) {
  return __builtin_amdgcn_exp2f(x);   // raw v_exp_f32
}

// ---------------- Kernel 1: projections via MFMA (fp32 -> bf16) -------------
// 512 blocks x 256 threads (4 waves). Block = (b, 32 columns); wave roles:
// w0: V rows 0-31, w1: V rows 32-63, w2: Q (from x_opt), w3: K (from x_sar).
// V written key-blocked vf2[b][kb=key/16][ch][kk=key%16]; K packed [n][8].
__global__ __launch_bounds__(256) void proj_kernel(
    const float* __restrict__ x_opt, const float* __restrict__ x_sar,
    const float* __restrict__ wq, const float* __restrict__ bq,
    const float* __restrict__ wk, const float* __restrict__ bk,
    const float* __restrict__ wvp, const float* __restrict__ bv,
    uint16_t* __restrict__ qf, uint16_t* __restrict__ kfp,
    uint16_t* __restrict__ vf2)
{
  const int tid = threadIdx.x;
  const int w = tid >> 6;       // wave role
  const int l = tid & 63;
  const int x = l & 31;
  const int hi = l >> 5;

  const int id = blockIdx.x;
  const int b = id >> 7;
  const int n0 = (id & 127) * 32;
  const size_t xbase = (size_t)b * CDIM * NDIM;

  // ---- X B-fragment (lane = col n0+x, regs = 8 k along kc*16 + 8hi + j)
  const float* xsrc = (w == 2) ? x_opt : x_sar;
  bf16x8 xB[4];
#pragma unroll
  for (int kc = 0; kc < 4; kc++) {
    float sv[8];
#pragma unroll
    for (int j = 0; j < 8; j++)
      sv[j] = xsrc[xbase + (size_t)(kc * 16 + hi * 8 + j) * NDIM + n0 + x];
    U4B us;
    us.u = make_uint4(cvtpk(sv[0], sv[1]), cvtpk(sv[2], sv[3]),
                      cvtpk(sv[4], sv[5]), cvtpk(sv[6], sv[7]));
    xB[kc] = us.b;
  }

  // ---- W A-fragment
  bf16x8 aF[4];
#pragma unroll
  for (int kc = 0; kc < 4; kc++) {
    U4B ua;
    ua.u = make_uint4(0u, 0u, 0u, 0u);
    if (w < 2) {
      const float* wr = wvp + (w * 32 + x) * 64 + kc * 16 + hi * 8;
      float4 wa = ((const float4*)wr)[0];
      float4 wb = ((const float4*)wr)[1];
      ua.u = make_uint4(cvtpk(wa.x, wa.y), cvtpk(wa.z, wa.w),
                        cvtpk(wb.x, wb.y), cvtpk(wb.z, wb.w));
    } else if (x < 8) {
      const float* wr = ((w == 2) ? wq : wk) + x * 64 + kc * 16 + hi * 8;
      float4 wa = ((const float4*)wr)[0];
      float4 wb = ((const float4*)wr)[1];
      ua.u = make_uint4(cvtpk(wa.x, wa.y), cvtpk(wa.z, wa.w),
                        cvtpk(wb.x, wb.y), cvtpk(wb.z, wb.w));
    }
    aF[kc] = ua.b;
  }

  const f32x16 z16 = {0.f,0.f,0.f,0.f, 0.f,0.f,0.f,0.f,
                      0.f,0.f,0.f,0.f, 0.f,0.f,0.f,0.f};
  f32x16 acc = z16;
#pragma unroll
  for (int kc = 0; kc < 4; kc++)
    acc = __builtin_amdgcn_mfma_f32_32x32x16_bf16(aF[kc], xB[kc], acc, 0, 0, 0);

  if (w < 2) {
    // V stores into blocked layout: kb = (n0+x)/16, kk = (n0+x)%16
    const size_t kbbase = (size_t)b * 256 + (n0 >> 4) + (x >> 4);
    const int kk = x & 15;
#pragma unroll
    for (int r = 0; r < 16; r++) {
      const int row = w * 32 + (r & 3) + 8 * (r >> 2) + 4 * hi;
      vf2[(kbbase * 64 + row) * 16 + kk] = f2bf(acc[r] + bv[row]);
    }
  } else if (w == 2) {
    // Q store: regs 0-3 hold d = 4hi + r; layout [n][16], zero upper 8
    float gv[4];
#pragma unroll
    for (int r = 0; r < 4; r++) gv[r] = (acc[r] + bq[4 * hi + r]) * LOG2E;
    const size_t nrow = ((size_t)b * NDIM + n0 + x) * 16;
    uint2 st;
    st.x = cvtpk(gv[0], gv[1]); st.y = cvtpk(gv[2], gv[3]);
    *(uint2*)(qf + nrow + hi * 4) = st;
    if (hi == 0) {
      const uint4 z4 = make_uint4(0u, 0u, 0u, 0u);
      *(uint4*)(qf + nrow + 8) = z4;
    }
  } else {
    // K store: packed [n][8] (real d only)
    float gv[4];
#pragma unroll
    for (int r = 0; r < 4; r++) gv[r] = acc[r] + bk[4 * hi + r];
    uint2 st;
    st.x = cvtpk(gv[0], gv[1]); st.y = cvtpk(gv[2], gv[3]);
    *(uint2*)(kfp + ((size_t)b * NDIM + n0 + x) * 8 + hi * 4) = st;
  }
}

// ------------- Kernel 2: flash attention partial (K-split) -----------
// 2048 blocks x 256 threads; sp = id&15 (two spans per XCD's L2).
// NO LDS, NO barriers. Coalesced V (blocked layout) + packed K; 1-quarter
// register lookahead; 8 quarters per block. 8 blocks/CU available so the
// scheduler can keep 3-4 waves/SIMD resident to hide L2/chain latency.
__global__ __launch_bounds__(256, 4) void attn_kernel(
    const uint16_t* __restrict__ qf, const uint16_t* __restrict__ kfp,
    const uint16_t* __restrict__ vf2,
    uint16_t* __restrict__ po, float* __restrict__ ls)
{
  const int tid = threadIdx.x;
  const int w = tid >> 6;
  const int l = tid & 63;
  const int x = l & 31;       // query col (S,O) / key row (K-frag) / channel (V-frag)
  const int hi = l >> 5;

  const int id = blockIdx.x;           // 2048 = 16 sp x 32 qb x 4 b
  const int sp = id & 15;
  const int qb = (id >> 4) & 31;
  const int b = id >> 9;

  const int n0 = qb * 128;
  const int qrow = n0 + w * 32 + x;

  U4B qfr;
  qfr.u = *(const uint4*)(qf + ((size_t)b * NDIM + qrow) * 16 + hi * 8);

  const uint32_t hmask = hi ? 0u : 0xFFFFFFFFu;   // zero k=8..15 half

  // per-lane bases; all loop offsets are compile-time immediates (u16 units)
  const uint16_t* kbase = kfp + ((size_t)b * NDIM + sp * SPAN + x) * 8;
  // vf2 idx: ((b*256 + sp*16 + kb)*64 + ch)*16 + kk; lane part: x*16 + 8hi
  const uint16_t* vbase =
      vf2 + (((size_t)b * 256 + sp * 16) * 64 + x) * 16 + hi * 8;

  const f32x16 z16 = {0.f,0.f,0.f,0.f, 0.f,0.f,0.f,0.f,
                      0.f,0.f,0.f,0.f, 0.f,0.f,0.f,0.f};
  f32x16 oacc0 = z16, oacc1 = z16;
  float lacc[4] = {0.f, 0.f, 0.f, 0.f};

  // prologue: quarter-0 K and V fragments
  uint4 kc   = *(const uint4*)(kbase);
  uint4 va00 = *(const uint4*)(vbase);           // sub0 ch 0-31
  uint4 va01 = *(const uint4*)(vbase + 512);     // sub0 ch 32-63
  uint4 va10 = *(const uint4*)(vbase + 1024);    // sub1 ch 0-31
  uint4 va11 = *(const uint4*)(vbase + 1536);    // sub1 ch 32-63

#pragma unroll
  for (int gq = 0; gq < NQ4; gq++) {
    // ---- prefetch quarter gq+1 (final iteration overruns into adjacent
    // ws region: allocated memory, value dead)
    const int vo = (gq + 1) * 2048;
    uint4 kn   = *(const uint4*)(kbase + (gq + 1) * 256);
    uint4 vn00 = *(const uint4*)(vbase + vo);
    uint4 vn01 = *(const uint4*)(vbase + vo + 512);
    uint4 vn10 = *(const uint4*)(vbase + vo + 1024);
    uint4 vn11 = *(const uint4*)(vbase + vo + 1536);

    // ---- scores S^T (32 keys x 32 queries), lane(q=x,hi):
    // key = (r&3) + 8*(r>>2) + 4hi
    U4B ka;
    ka.u.x = kc.x & hmask; ka.u.y = kc.y & hmask;
    ka.u.z = kc.z & hmask; ka.u.w = kc.w & hmask;
    f32x16 s = __builtin_amdgcn_mfma_f32_32x32x16_bf16(ka.b, qfr.b, z16, 0, 0, 0);

    // ---- fused p = exp2(s) -> bf16 pack -> row-sum (2 live p floats)
    uint32_t W[8];
#pragma unroll
    for (int j = 0; j < 8; j++) {
      const float p0 = fexp2(s[2 * j]);
      const float p1 = fexp2(s[2 * j + 1]);
      W[j] = cvtpk(p0, p1);
      lacc[j & 3] += p0 + p1;
    }

    // ---- PV: O^T += V^T . P^T (2 sub-chunks x 2 channel-blocks)
    __builtin_amdgcn_s_setprio(1);
    {
      uint32_t a0 = W[0], b0 = W[2], a1 = W[1], b1 = W[3];
      asm("v_permlane32_swap_b32 %0, %1" : "+v"(a0), "+v"(b0));
      asm("v_permlane32_swap_b32 %0, %1" : "+v"(a1), "+v"(b1));
      U4B pf, va, vb;
      pf.u = make_uint4(a0, a1, b0, b1);
      va.u = va00; vb.u = va01;
      oacc0 = __builtin_amdgcn_mfma_f32_32x32x16_bf16(va.b, pf.b, oacc0, 0, 0, 0);
      oacc1 = __builtin_amdgcn_mfma_f32_32x32x16_bf16(vb.b, pf.b, oacc1, 0, 0, 0);
    }
    {
      uint32_t a0 = W[4], b0 = W[6], a1 = W[5], b1 = W[7];
      asm("v_permlane32_swap_b32 %0, %1" : "+v"(a0), "+v"(b0));
      asm("v_permlane32_swap_b32 %0, %1" : "+v"(a1), "+v"(b1));
      U4B pf, va, vb;
      pf.u = make_uint4(a0, a1, b0, b1);
      va.u = va10; vb.u = va11;
      oacc0 = __builtin_amdgcn_mfma_f32_32x32x16_bf16(va.b, pf.b, oacc0, 0, 0, 0);
      oacc1 = __builtin_amdgcn_mfma_f32_32x32x16_bf16(vb.b, pf.b, oacc1, 0, 0, 0);
    }
    __builtin_amdgcn_s_setprio(0);

    kc = kn; va00 = vn00; va01 = vn01; va10 = vn10; va11 = vn11;
  }

  // ---- epilogue: raw (unnormalized) partial O in bf16 + row-sum l
  uint16_t* prow = po + (((size_t)sp * 4 + b) * NDIM + qrow) * CDIM;
#pragma unroll
  for (int cb = 0; cb < 2; cb++) {
    const f32x16 oa = (cb == 0) ? oacc0 : oacc1;
#pragma unroll
    for (int u = 0; u < 4; u++) {
      uint2 st;
      st.x = cvtpk(oa[u * 4 + 0], oa[u * 4 + 1]);
      st.y = cvtpk(oa[u * 4 + 2], oa[u * 4 + 3]);
      *(uint2*)(prow + cb * 32 + u * 8 + hi * 4) = st;
    }
  }
  float ltot = (lacc[0] + lacc[1]) + (lacc[2] + lacc[3]);
  ltot += __shfl_xor(ltot, 32);
  if (hi == 0)
    ls[((size_t)sp * 4 + b) * NDIM + qrow] = ltot;
}

// ---------------- Kernel 3: split merge + gamma*O + residual ----------------
// 512 blocks x 256 threads; block = (b, 32 queries); transpose via LDS.
// out = gamma * (sum_s po_s) / (sum_s l_s) + x_opt
__global__ __launch_bounds__(256) void merge_kernel(
    const uint16_t* __restrict__ po, const float* __restrict__ ls,
    const float* __restrict__ x_opt, const float* __restrict__ gamma,
    float* __restrict__ out)
{
  __shared__ float ot[32][65];
  const int tid = threadIdx.x;
  const int b = blockIdx.x >> 7;
  const int n0 = (blockIdx.x & 127) * 32;
  {
    const int q = tid >> 3;
    const int co = (tid & 7) * 8;
    const int nq = n0 + q;
    float wsum = 0.f;
    float acc[8] = {0.f, 0.f, 0.f, 0.f, 0.f, 0.f, 0.f, 0.f};
#pragma unroll
    for (int s = 0; s < NSPLIT; s++) {
      wsum += ls[((size_t)s * 4 + b) * NDIM + nq];
      const uint4 pv = *(const uint4*)(po + (((size_t)s * 4 + b) * NDIM + nq) * CDIM + co);
      const uint32_t* pw = (const uint32_t*)&pv;
#pragma unroll
      for (int j = 0; j < 4; j++) {
        acc[j * 2 + 0] += __uint_as_float(pw[j] << 16);
        acc[j * 2 + 1] += __uint_as_float(pw[j] & 0xFFFF0000u);
      }
    }
    const float inv = 1.f / wsum;
#pragma unroll
    for (int j = 0; j < 8; j++) ot[q][co + j] = acc[j] * inv;
  }
  __syncthreads();
  {
    const float gm = gamma[0];
    const int c = tid >> 2;
    const int j8 = (tid & 3) * 8;
    const float* xp = x_opt + ((size_t)b * CDIM + c) * NDIM + n0 + j8;
    float* op = out + ((size_t)b * CDIM + c) * NDIM + n0 + j8;
#pragma unroll
    for (int h = 0; h < 2; h++) {
      float4 xv = ((const float4*)xp)[h];
      float4 ov;
      ov.x = gm * ot[j8 + h * 4 + 0][c] + xv.x;
      ov.y = gm * ot[j8 + h * 4 + 1][c] + xv.y;
      ov.z = gm * ot[j8 + h * 4 + 2][c] + xv.z;
      ov.w = gm * ot[j8 + h * 4 + 3][c] + xv.w;
      ((float4*)op)[h] = ov;
    }
  }
}

extern "C" void kernel_launch(void* const* d_in, const int* in_sizes, int n_in,
                              void* d_out, int out_size, void* d_ws, size_t ws_size,
                              hipStream_t stream) {
  const float* x_opt = (const float*)d_in[0];
  const float* x_sar = (const float*)d_in[1];
  const float* wq    = (const float*)d_in[2];
  const float* bq    = (const float*)d_in[3];
  const float* wk    = (const float*)d_in[4];
  const float* bk    = (const float*)d_in[5];
  const float* wvp   = (const float*)d_in[6];
  const float* bv    = (const float*)d_in[7];
  const float* gamma = (const float*)d_in[8];
  float* outp = (float*)d_out;

  // ws: qf 512K | kfp 256K(+pad to 1M) | vf2 2M | po(bf16) 32M | ls 1M
  uint16_t* qf  = (uint16_t*)d_ws;
  uint16_t* kfp = (uint16_t*)((char*)d_ws + 524288);
  uint16_t* vf2 = (uint16_t*)((char*)d_ws + 1048576);
  uint16_t* po  = (uint16_t*)((char*)d_ws + 3145728);
  float* lsp    = (float*)((char*)d_ws + 36700160);

  proj_kernel<<<512, 256, 0, stream>>>(x_opt, x_sar, wq, bq, wk, bk, wvp, bv,
                                       qf, kfp, vf2);
  attn_kernel<<<2048, 256, 0, stream>>>(qf, kfp, vf2, po, lsp);
  merge_kernel<<<512, 256, 0, stream>>>(po, lsp, x_opt, gamma, outp);
}

// Round 15
// 36.662 us; speedup vs baseline: 1.4982x; 1.1214x over previous
//
#include <hip/hip_runtime.h>
#include <hip/hip_bf16.h>
#include <stdint.h>

#define NDIM 4096
#define CDIM 64
#define NSPLIT 8
#define SPAN (NDIM / NSPLIT)   // 512 keys per split
#define NQ4 (SPAN / 32)        // 16 quarters per block
#define LOG2E 1.44269504088896f

typedef float f32x4 __attribute__((ext_vector_type(4)));
typedef float f32x16 __attribute__((ext_vector_type(16)));
typedef short bf16x8 __attribute__((ext_vector_type(8)));
union U4B { uint4 u; bf16x8 b; };

// single-instruction packed f32->bf16 (RNE), lo -> bits[15:0], hi -> bits[31:16]
static __device__ __forceinline__ uint32_t cvtpk(float lo, float hi) {
  uint32_t r;
  asm("v_cvt_pk_bf16_f32 %0, %1, %2" : "=v"(r) : "v"(lo), "v"(hi));
  return r;
}
static __device__ __forceinline__ uint16_t f2bf(float f) {
  uint32_t r;
  asm("v_cvt_pk_bf16_f32 %0, %1, %1" : "=v"(r) : "v"(f));
  return (uint16_t)r;
}
static __device__ __forceinline__ float fexp2(float x) {
  return __builtin_amdgcn_exp2f(x);   // raw v_exp_f32
}

// ---------------- Kernel 1: projections via MFMA (fp32 -> bf16) -------------
// 512 blocks x 256 threads (4 waves). Block = (b, 32 columns); wave roles:
// w0: V rows 0-31, w1: V rows 32-63, w2: Q (from x_opt), w3: K (from x_sar).
// V written key-blocked vf2[b][kb=key/16][ch][kk=key%16]; K packed [n][8].
__global__ __launch_bounds__(256) void proj_kernel(
    const float* __restrict__ x_opt, const float* __restrict__ x_sar,
    const float* __restrict__ wq, const float* __restrict__ bq,
    const float* __restrict__ wk, const float* __restrict__ bk,
    const float* __restrict__ wvp, const float* __restrict__ bv,
    uint16_t* __restrict__ qf, uint16_t* __restrict__ kfp,
    uint16_t* __restrict__ vf2)
{
  const int tid = threadIdx.x;
  const int w = tid >> 6;       // wave role
  const int l = tid & 63;
  const int x = l & 31;
  const int hi = l >> 5;

  const int id = blockIdx.x;
  const int b = id >> 7;
  const int n0 = (id & 127) * 32;
  const size_t xbase = (size_t)b * CDIM * NDIM;

  // ---- X B-fragment (lane = col n0+x, regs = 8 k along kc*16 + 8hi + j)
  const float* xsrc = (w == 2) ? x_opt : x_sar;
  bf16x8 xB[4];
#pragma unroll
  for (int kc = 0; kc < 4; kc++) {
    float sv[8];
#pragma unroll
    for (int j = 0; j < 8; j++)
      sv[j] = xsrc[xbase + (size_t)(kc * 16 + hi * 8 + j) * NDIM + n0 + x];
    U4B us;
    us.u = make_uint4(cvtpk(sv[0], sv[1]), cvtpk(sv[2], sv[3]),
                      cvtpk(sv[4], sv[5]), cvtpk(sv[6], sv[7]));
    xB[kc] = us.b;
  }

  // ---- W A-fragment
  bf16x8 aF[4];
#pragma unroll
  for (int kc = 0; kc < 4; kc++) {
    U4B ua;
    ua.u = make_uint4(0u, 0u, 0u, 0u);
    if (w < 2) {
      const float* wr = wvp + (w * 32 + x) * 64 + kc * 16 + hi * 8;
      float4 wa = ((const float4*)wr)[0];
      float4 wb = ((const float4*)wr)[1];
      ua.u = make_uint4(cvtpk(wa.x, wa.y), cvtpk(wa.z, wa.w),
                        cvtpk(wb.x, wb.y), cvtpk(wb.z, wb.w));
    } else if (x < 8) {
      const float* wr = ((w == 2) ? wq : wk) + x * 64 + kc * 16 + hi * 8;
      float4 wa = ((const float4*)wr)[0];
      float4 wb = ((const float4*)wr)[1];
      ua.u = make_uint4(cvtpk(wa.x, wa.y), cvtpk(wa.z, wa.w),
                        cvtpk(wb.x, wb.y), cvtpk(wb.z, wb.w));
    }
    aF[kc] = ua.b;
  }

  const f32x16 z16 = {0.f,0.f,0.f,0.f, 0.f,0.f,0.f,0.f,
                      0.f,0.f,0.f,0.f, 0.f,0.f,0.f,0.f};
  f32x16 acc = z16;
#pragma unroll
  for (int kc = 0; kc < 4; kc++)
    acc = __builtin_amdgcn_mfma_f32_32x32x16_bf16(aF[kc], xB[kc], acc, 0, 0, 0);

  if (w < 2) {
    // V stores into blocked layout: kb = (n0+x)/16, kk = (n0+x)%16
    const size_t kbbase = (size_t)b * 256 + (n0 >> 4) + (x >> 4);
    const int kk = x & 15;
#pragma unroll
    for (int r = 0; r < 16; r++) {
      const int row = w * 32 + (r & 3) + 8 * (r >> 2) + 4 * hi;
      vf2[(kbbase * 64 + row) * 16 + kk] = f2bf(acc[r] + bv[row]);
    }
  } else if (w == 2) {
    // Q store: regs 0-3 hold d = 4hi + r; layout [n][16], zero upper 8
    float gv[4];
#pragma unroll
    for (int r = 0; r < 4; r++) gv[r] = (acc[r] + bq[4 * hi + r]) * LOG2E;
    const size_t nrow = ((size_t)b * NDIM + n0 + x) * 16;
    uint2 st;
    st.x = cvtpk(gv[0], gv[1]); st.y = cvtpk(gv[2], gv[3]);
    *(uint2*)(qf + nrow + hi * 4) = st;
    if (hi == 0) {
      const uint4 z4 = make_uint4(0u, 0u, 0u, 0u);
      *(uint4*)(qf + nrow + 8) = z4;
    }
  } else {
    // K store: packed [n][8] (real d only)
    float gv[4];
#pragma unroll
    for (int r = 0; r < 4; r++) gv[r] = acc[r] + bk[4 * hi + r];
    uint2 st;
    st.x = cvtpk(gv[0], gv[1]); st.y = cvtpk(gv[2], gv[3]);
    *(uint2*)(kfp + ((size_t)b * NDIM + n0 + x) * 8 + hi * 4) = st;
  }
}

// ------------- Kernel 2: flash attention partial (K-split) -----------
// 1024 blocks x 256 threads, sp = id&7 pins KV span to one XCD's L2.
// NO LDS, NO barriers; coalesced blocked-V + packed-K; 1-quarter register
// lookahead. K hi-half garbage is harmless: Q's upper-8 k lanes are zero,
// so MFMA contributes exactly 0 (no mask needed). Partial O^T written
// channel-major (po2[sp][b][c][n]) -> every store is one contiguous line.
__global__ __launch_bounds__(256, 4) void attn_kernel(
    const uint16_t* __restrict__ qf, const uint16_t* __restrict__ kfp,
    const uint16_t* __restrict__ vf2,
    uint16_t* __restrict__ po2, float* __restrict__ ls)
{
  const int tid = threadIdx.x;
  const int w = tid >> 6;
  const int l = tid & 63;
  const int x = l & 31;       // query col (S,O) / key row (K-frag) / channel (V-frag)
  const int hi = l >> 5;

  const int id = blockIdx.x;           // 1024 = 8 sp x 32 qb x 4 b
  const int sp = id & 7;
  const int qb = (id >> 3) & 31;
  const int b = id >> 8;

  const int n0 = qb * 128;
  const int qrow = n0 + w * 32 + x;

  U4B qfr;
  qfr.u = *(const uint4*)(qf + ((size_t)b * NDIM + qrow) * 16 + hi * 8);

  // per-lane bases; all loop offsets are compile-time immediates (u16 units)
  const uint16_t* kbase = kfp + ((size_t)b * NDIM + sp * SPAN + x) * 8;
  // vf2 idx: ((b*256 + sp*64/... + kb)*64 + ch)*16 + kk; lane part: x*16 + 8hi
  const uint16_t* vbase =
      vf2 + (((size_t)b * 256 + sp * 32) * 64 + x) * 16 + hi * 8;

  const f32x16 z16 = {0.f,0.f,0.f,0.f, 0.f,0.f,0.f,0.f,
                      0.f,0.f,0.f,0.f, 0.f,0.f,0.f,0.f};
  f32x16 oacc0 = z16, oacc1 = z16;
  float lacc[4] = {0.f, 0.f, 0.f, 0.f};

  // prologue: quarter-0 K and V fragments
  uint4 kc   = *(const uint4*)(kbase);
  uint4 va00 = *(const uint4*)(vbase);           // sub0 ch 0-31
  uint4 va01 = *(const uint4*)(vbase + 512);     // sub0 ch 32-63
  uint4 va10 = *(const uint4*)(vbase + 1024);    // sub1 ch 0-31
  uint4 va11 = *(const uint4*)(vbase + 1536);    // sub1 ch 32-63

#pragma unroll
  for (int gq = 0; gq < NQ4; gq++) {
    // ---- prefetch quarter gq+1 (final iteration overruns into adjacent
    // ws pad region: allocated memory, value dead)
    const int vo = (gq + 1) * 2048;
    uint4 kn   = *(const uint4*)(kbase + (gq + 1) * 256);
    uint4 vn00 = *(const uint4*)(vbase + vo);
    uint4 vn01 = *(const uint4*)(vbase + vo + 512);
    uint4 vn10 = *(const uint4*)(vbase + vo + 1024);
    uint4 vn11 = *(const uint4*)(vbase + vo + 1536);

    // ---- scores S^T (32 keys x 32 queries), lane(q=x,hi):
    // key = (r&3) + 8*(r>>2) + 4hi. K hi-half garbage x Q zero = 0.
    U4B ka; ka.u = kc;
    f32x16 s = __builtin_amdgcn_mfma_f32_32x32x16_bf16(ka.b, qfr.b, z16, 0, 0, 0);

    // ---- fused p = exp2(s) -> bf16 pack -> row-sum (2 live p floats)
    uint32_t W[8];
#pragma unroll
    for (int j = 0; j < 8; j++) {
      const float p0 = fexp2(s[2 * j]);
      const float p1 = fexp2(s[2 * j + 1]);
      W[j] = cvtpk(p0, p1);
      lacc[j & 3] += p0 + p1;
    }

    // ---- PV: O^T += V^T . P^T (2 sub-chunks x 2 channel-blocks)
    __builtin_amdgcn_s_setprio(1);
    {
      uint32_t a0 = W[0], b0 = W[2], a1 = W[1], b1 = W[3];
      asm("v_permlane32_swap_b32 %0, %1" : "+v"(a0), "+v"(b0));
      asm("v_permlane32_swap_b32 %0, %1" : "+v"(a1), "+v"(b1));
      U4B pf, va, vb;
      pf.u = make_uint4(a0, a1, b0, b1);
      va.u = va00; vb.u = va01;
      oacc0 = __builtin_amdgcn_mfma_f32_32x32x16_bf16(va.b, pf.b, oacc0, 0, 0, 0);
      oacc1 = __builtin_amdgcn_mfma_f32_32x32x16_bf16(vb.b, pf.b, oacc1, 0, 0, 0);
    }
    {
      uint32_t a0 = W[4], b0 = W[6], a1 = W[5], b1 = W[7];
      asm("v_permlane32_swap_b32 %0, %1" : "+v"(a0), "+v"(b0));
      asm("v_permlane32_swap_b32 %0, %1" : "+v"(a1), "+v"(b1));
      U4B pf, va, vb;
      pf.u = make_uint4(a0, a1, b0, b1);
      va.u = va10; vb.u = va11;
      oacc0 = __builtin_amdgcn_mfma_f32_32x32x16_bf16(va.b, pf.b, oacc0, 0, 0, 0);
      oacc1 = __builtin_amdgcn_mfma_f32_32x32x16_bf16(vb.b, pf.b, oacc1, 0, 0, 0);
    }
    __builtin_amdgcn_s_setprio(0);

    kc = kn; va00 = vn00; va01 = vn01; va10 = vn10; va11 = vn11;
  }

  // ---- epilogue: raw partial O^T, channel-major po2[(sp*256+b*64+c)][n]
  // lane x writes 2B at qrow = contiguous 64B line per 32-lane half
  {
    uint16_t* pb = po2 + ((size_t)(sp * 256 + b * 64 + hi * 4)) * NDIM + qrow;
#pragma unroll
    for (int r = 0; r < 16; r++) {
      const size_t off = (size_t)((r & 3) + 8 * (r >> 2)) * NDIM;
      pb[off] = f2bf(oacc0[r]);
      pb[off + (size_t)32 * NDIM] = f2bf(oacc1[r]);
    }
  }
  float ltot = (lacc[0] + lacc[1]) + (lacc[2] + lacc[3]);
  ltot += __shfl_xor(ltot, 32);
  if (hi == 0)
    ls[((size_t)sp * 4 + b) * NDIM + qrow] = ltot;
}

// ---------------- Kernel 3: split merge + gamma*O + residual ----------------
// 512 blocks x 256 threads; one thread = 8 consecutive n for one (b,c).
// All reads/writes fully coalesced along n; no LDS.
// out = gamma * (sum_s po2_s) / (sum_s l_s) + x_opt
__global__ __launch_bounds__(256) void merge_kernel(
    const uint16_t* __restrict__ po2, const float* __restrict__ ls,
    const float* __restrict__ x_opt, const float* __restrict__ gamma,
    float* __restrict__ out)
{
  const int idx = blockIdx.x * 256 + threadIdx.x;   // 131072 threads
  const int n8 = (idx & 511) << 3;
  const int row = idx >> 9;              // b*64 + c
  const int b = row >> 6;

  float acc[8] = {0.f, 0.f, 0.f, 0.f, 0.f, 0.f, 0.f, 0.f};
  f32x4 ws0 = {0.f, 0.f, 0.f, 0.f};
  f32x4 ws1 = {0.f, 0.f, 0.f, 0.f};
#pragma unroll
  for (int s = 0; s < NSPLIT; s++) {
    const uint4 pv = *(const uint4*)(po2 + ((size_t)s * 256 + row) * NDIM + n8);
    const uint32_t* pw = (const uint32_t*)&pv;
#pragma unroll
    for (int j = 0; j < 4; j++) {
      acc[j * 2 + 0] += __uint_as_float(pw[j] << 16);
      acc[j * 2 + 1] += __uint_as_float(pw[j] & 0xFFFF0000u);
    }
    const float* lp = ls + ((size_t)s * 4 + b) * NDIM + n8;
    ws0 += *(const f32x4*)(lp);
    ws1 += *(const f32x4*)(lp + 4);
  }
  const float gm = gamma[0];
  const float* xp = x_opt + (size_t)row * NDIM + n8;
  float* op = out + (size_t)row * NDIM + n8;
  float4 x0 = ((const float4*)xp)[0];
  float4 x1 = ((const float4*)xp)[1];
  float4 o0, o1;
  o0.x = gm * acc[0] / ws0[0] + x0.x;
  o0.y = gm * acc[1] / ws0[1] + x0.y;
  o0.z = gm * acc[2] / ws0[2] + x0.z;
  o0.w = gm * acc[3] / ws0[3] + x0.w;
  o1.x = gm * acc[4] / ws1[0] + x1.x;
  o1.y = gm * acc[5] / ws1[1] + x1.y;
  o1.z = gm * acc[6] / ws1[2] + x1.z;
  o1.w = gm * acc[7] / ws1[3] + x1.w;
  ((float4*)op)[0] = o0;
  ((float4*)op)[1] = o1;
}

extern "C" void kernel_launch(void* const* d_in, const int* in_sizes, int n_in,
                              void* d_out, int out_size, void* d_ws, size_t ws_size,
                              hipStream_t stream) {
  const float* x_opt = (const float*)d_in[0];
  const float* x_sar = (const float*)d_in[1];
  const float* wq    = (const float*)d_in[2];
  const float* bq    = (const float*)d_in[3];
  const float* wk    = (const float*)d_in[4];
  const float* bk    = (const float*)d_in[5];
  const float* wvp   = (const float*)d_in[6];
  const float* bv    = (const float*)d_in[7];
  const float* gamma = (const float*)d_in[8];
  float* outp = (float*)d_out;

  // ws: qf 512K | kfp 256K(+256K pad) | vf2 2M | po2(bf16) 16M | ls 512K
  uint16_t* qf  = (uint16_t*)d_ws;
  uint16_t* kfp = (uint16_t*)((char*)d_ws + 524288);
  uint16_t* vf2 = (uint16_t*)((char*)d_ws + 1048576);
  uint16_t* po2 = (uint16_t*)((char*)d_ws + 3145728);
  float* lsp    = (float*)((char*)d_ws + 19922944);

  proj_kernel<<<512, 256, 0, stream>>>(x_opt, x_sar, wq, bq, wk, bk, wvp, bv,
                                       qf, kfp, vf2);
  attn_kernel<<<1024, 256, 0, stream>>>(qf, kfp, vf2, po2, lsp);
  merge_kernel<<<512, 256, 0, stream>>>(po2, lsp, x_opt, gamma, outp);
}

// Round 16
// 36.631 us; speedup vs baseline: 1.4995x; 1.0008x over previous
//
#include <hip/hip_runtime.h>
#include <hip/hip_bf16.h>
#include <stdint.h>

#define NDIM 4096
#define CDIM 64
#define NSPLIT 8
#define SPAN (NDIM / NSPLIT)   // 512 keys per split
#define NQ4 (SPAN / 32)        // 16 quarters per block
#define LOG2E 1.44269504088896f

typedef float f32x4 __attribute__((ext_vector_type(4)));
typedef float f32x16 __attribute__((ext_vector_type(16)));
typedef short bf16x8 __attribute__((ext_vector_type(8)));
union U4B { uint4 u; bf16x8 b; };

// single-instruction packed f32->bf16 (RNE), lo -> bits[15:0], hi -> bits[31:16]
static __device__ __forceinline__ uint32_t cvtpk(float lo, float hi) {
  uint32_t r;
  asm("v_cvt_pk_bf16_f32 %0, %1, %2" : "=v"(r) : "v"(lo), "v"(hi));
  return r;
}
static __device__ __forceinline__ uint16_t f2bf(float f) {
  uint32_t r;
  asm("v_cvt_pk_bf16_f32 %0, %1, %1" : "=v"(r) : "v"(f));
  return (uint16_t)r;
}
static __device__ __forceinline__ float fexp2(float x) {
  return __builtin_amdgcn_exp2f(x);   // raw v_exp_f32
}

// ---------------- Kernel 1: projections via MFMA (fp32 -> bf16) -------------
// 512 blocks x 256 threads (4 waves). Block = (b, 32 columns); wave roles:
// w0: V rows 0-31, w1: V rows 32-63, w2: Q (from x_opt), w3: K (from x_sar).
// V written key-blocked vf2[b][kb=key/16][ch][kk=key%16]; K packed [n][8].
__global__ __launch_bounds__(256) void proj_kernel(
    const float* __restrict__ x_opt, const float* __restrict__ x_sar,
    const float* __restrict__ wq, const float* __restrict__ bq,
    const float* __restrict__ wk, const float* __restrict__ bk,
    const float* __restrict__ wvp, const float* __restrict__ bv,
    uint16_t* __restrict__ qf, uint16_t* __restrict__ kfp,
    uint16_t* __restrict__ vf2)
{
  const int tid = threadIdx.x;
  const int w = tid >> 6;       // wave role
  const int l = tid & 63;
  const int x = l & 31;
  const int hi = l >> 5;

  const int id = blockIdx.x;
  const int b = id >> 7;
  const int n0 = (id & 127) * 32;
  const size_t xbase = (size_t)b * CDIM * NDIM;

  // ---- X B-fragment (lane = col n0+x, regs = 8 k along kc*16 + 8hi + j)
  const float* xsrc = (w == 2) ? x_opt : x_sar;
  bf16x8 xB[4];
#pragma unroll
  for (int kc = 0; kc < 4; kc++) {
    float sv[8];
#pragma unroll
    for (int j = 0; j < 8; j++)
      sv[j] = xsrc[xbase + (size_t)(kc * 16 + hi * 8 + j) * NDIM + n0 + x];
    U4B us;
    us.u = make_uint4(cvtpk(sv[0], sv[1]), cvtpk(sv[2], sv[3]),
                      cvtpk(sv[4], sv[5]), cvtpk(sv[6], sv[7]));
    xB[kc] = us.b;
  }

  // ---- W A-fragment
  bf16x8 aF[4];
#pragma unroll
  for (int kc = 0; kc < 4; kc++) {
    U4B ua;
    ua.u = make_uint4(0u, 0u, 0u, 0u);
    if (w < 2) {
      const float* wr = wvp + (w * 32 + x) * 64 + kc * 16 + hi * 8;
      float4 wa = ((const float4*)wr)[0];
      float4 wb = ((const float4*)wr)[1];
      ua.u = make_uint4(cvtpk(wa.x, wa.y), cvtpk(wa.z, wa.w),
                        cvtpk(wb.x, wb.y), cvtpk(wb.z, wb.w));
    } else if (x < 8) {
      const float* wr = ((w == 2) ? wq : wk) + x * 64 + kc * 16 + hi * 8;
      float4 wa = ((const float4*)wr)[0];
      float4 wb = ((const float4*)wr)[1];
      ua.u = make_uint4(cvtpk(wa.x, wa.y), cvtpk(wa.z, wa.w),
                        cvtpk(wb.x, wb.y), cvtpk(wb.z, wb.w));
    }
    aF[kc] = ua.b;
  }

  const f32x16 z16 = {0.f,0.f,0.f,0.f, 0.f,0.f,0.f,0.f,
                      0.f,0.f,0.f,0.f, 0.f,0.f,0.f,0.f};
  f32x16 acc = z16;
#pragma unroll
  for (int kc = 0; kc < 4; kc++)
    acc = __builtin_amdgcn_mfma_f32_32x32x16_bf16(aF[kc], xB[kc], acc, 0, 0, 0);

  if (w < 2) {
    // V stores into blocked layout: kb = (n0+x)/16, kk = (n0+x)%16
    const size_t kbbase = (size_t)b * 256 + (n0 >> 4) + (x >> 4);
    const int kk = x & 15;
#pragma unroll
    for (int r = 0; r < 16; r++) {
      const int row = w * 32 + (r & 3) + 8 * (r >> 2) + 4 * hi;
      vf2[(kbbase * 64 + row) * 16 + kk] = f2bf(acc[r] + bv[row]);
    }
  } else if (w == 2) {
    // Q store: regs 0-3 hold d = 4hi + r; layout [n][16], zero upper 8
    float gv[4];
#pragma unroll
    for (int r = 0; r < 4; r++) gv[r] = (acc[r] + bq[4 * hi + r]) * LOG2E;
    const size_t nrow = ((size_t)b * NDIM + n0 + x) * 16;
    uint2 st;
    st.x = cvtpk(gv[0], gv[1]); st.y = cvtpk(gv[2], gv[3]);
    *(uint2*)(qf + nrow + hi * 4) = st;
    if (hi == 0) {
      const uint4 z4 = make_uint4(0u, 0u, 0u, 0u);
      *(uint4*)(qf + nrow + 8) = z4;
    }
  } else {
    // K store: packed [n][8] (real d only)
    float gv[4];
#pragma unroll
    for (int r = 0; r < 4; r++) gv[r] = acc[r] + bk[4 * hi + r];
    uint2 st;
    st.x = cvtpk(gv[0], gv[1]); st.y = cvtpk(gv[2], gv[3]);
    *(uint2*)(kfp + ((size_t)b * NDIM + n0 + x) * 8 + hi * 4) = st;
  }
}

// ------------- Kernel 2: flash attention partial (K-split) -----------
// 1024 blocks x 256 threads, sp = id&7 pins KV span to one XCD's L2.
// NO LDS, NO barriers; coalesced blocked-V + packed-K. TWO-quarter register
// lookahead (3 live K/V sets, rotated by full-unroll SSA renaming) gives
// each load ~2 quarters of slack to cover L2/L3 latency. (256,3) bounds:
// ~135 live regs without spill -> 3 waves/SIMD.
__global__ __launch_bounds__(256, 3) void attn_kernel(
    const uint16_t* __restrict__ qf, const uint16_t* __restrict__ kfp,
    const uint16_t* __restrict__ vf2,
    uint16_t* __restrict__ po2, float* __restrict__ ls)
{
  const int tid = threadIdx.x;
  const int w = tid >> 6;
  const int l = tid & 63;
  const int x = l & 31;       // query col (S,O) / key row (K-frag) / channel (V-frag)
  const int hi = l >> 5;

  const int id = blockIdx.x;           // 1024 = 8 sp x 32 qb x 4 b
  const int sp = id & 7;
  const int qb = (id >> 3) & 31;
  const int b = id >> 8;

  const int n0 = qb * 128;
  const int qrow = n0 + w * 32 + x;

  U4B qfr;
  qfr.u = *(const uint4*)(qf + ((size_t)b * NDIM + qrow) * 16 + hi * 8);

  // per-lane bases; all loop offsets are compile-time immediates (u16 units)
  const uint16_t* kbase = kfp + ((size_t)b * NDIM + sp * SPAN + x) * 8;
  const uint16_t* vbase =
      vf2 + (((size_t)b * 256 + sp * 32) * 64 + x) * 16 + hi * 8;

  const f32x16 z16 = {0.f,0.f,0.f,0.f, 0.f,0.f,0.f,0.f,
                      0.f,0.f,0.f,0.f, 0.f,0.f,0.f,0.f};
  f32x16 oacc0 = z16, oacc1 = z16;
  float lacc[4] = {0.f, 0.f, 0.f, 0.f};

  // prologue: quarters 0 and 1 in flight (2-deep)
  uint4 kA = *(const uint4*)(kbase);
  uint4 vA0 = *(const uint4*)(vbase);
  uint4 vA1 = *(const uint4*)(vbase + 512);
  uint4 vA2 = *(const uint4*)(vbase + 1024);
  uint4 vA3 = *(const uint4*)(vbase + 1536);
  uint4 kB = *(const uint4*)(kbase + 256);
  uint4 vB0 = *(const uint4*)(vbase + 2048);
  uint4 vB1 = *(const uint4*)(vbase + 2048 + 512);
  uint4 vB2 = *(const uint4*)(vbase + 2048 + 1024);
  uint4 vB3 = *(const uint4*)(vbase + 2048 + 1536);

#pragma unroll
  for (int gq = 0; gq < NQ4; gq++) {
    // ---- issue quarter gq+2 (overrun past span lands in the adjacent ws
    // region -- allocated memory, value dead)
    const int vo = (gq + 2) * 2048;
    uint4 kC  = *(const uint4*)(kbase + (gq + 2) * 256);
    uint4 vC0 = *(const uint4*)(vbase + vo);
    uint4 vC1 = *(const uint4*)(vbase + vo + 512);
    uint4 vC2 = *(const uint4*)(vbase + vo + 1024);
    uint4 vC3 = *(const uint4*)(vbase + vo + 1536);

    // ---- scores S^T (32 keys x 32 queries), lane(q=x,hi):
    // key = (r&3) + 8*(r>>2) + 4hi. K hi-half garbage x Q zero = 0.
    U4B ka; ka.u = kA;
    f32x16 s = __builtin_amdgcn_mfma_f32_32x32x16_bf16(ka.b, qfr.b, z16, 0, 0, 0);

    // ---- fused p = exp2(s) -> bf16 pack -> row-sum (2 live p floats)
    uint32_t W[8];
#pragma unroll
    for (int j = 0; j < 8; j++) {
      const float p0 = fexp2(s[2 * j]);
      const float p1 = fexp2(s[2 * j + 1]);
      W[j] = cvtpk(p0, p1);
      lacc[j & 3] += p0 + p1;
    }

    // ---- PV: O^T += V^T . P^T (2 sub-chunks x 2 channel-blocks)
    __builtin_amdgcn_s_setprio(1);
    {
      uint32_t a0 = W[0], b0 = W[2], a1 = W[1], b1 = W[3];
      asm("v_permlane32_swap_b32 %0, %1" : "+v"(a0), "+v"(b0));
      asm("v_permlane32_swap_b32 %0, %1" : "+v"(a1), "+v"(b1));
      U4B pf, va, vb;
      pf.u = make_uint4(a0, a1, b0, b1);
      va.u = vA0; vb.u = vA1;
      oacc0 = __builtin_amdgcn_mfma_f32_32x32x16_bf16(va.b, pf.b, oacc0, 0, 0, 0);
      oacc1 = __builtin_amdgcn_mfma_f32_32x32x16_bf16(vb.b, pf.b, oacc1, 0, 0, 0);
    }
    {
      uint32_t a0 = W[4], b0 = W[6], a1 = W[5], b1 = W[7];
      asm("v_permlane32_swap_b32 %0, %1" : "+v"(a0), "+v"(b0));
      asm("v_permlane32_swap_b32 %0, %1" : "+v"(a1), "+v"(b1));
      U4B pf, va, vb;
      pf.u = make_uint4(a0, a1, b0, b1);
      va.u = vA2; vb.u = vA3;
      oacc0 = __builtin_amdgcn_mfma_f32_32x32x16_bf16(va.b, pf.b, oacc0, 0, 0, 0);
      oacc1 = __builtin_amdgcn_mfma_f32_32x32x16_bf16(vb.b, pf.b, oacc1, 0, 0, 0);
    }
    __builtin_amdgcn_s_setprio(0);

    // rotate (full unroll -> SSA renaming, no v_mov cost)
    kA = kB; vA0 = vB0; vA1 = vB1; vA2 = vB2; vA3 = vB3;
    kB = kC; vB0 = vC0; vB1 = vC1; vB2 = vC2; vB3 = vC3;
  }

  // ---- epilogue: raw partial O^T, channel-major po2[(sp*256+b*64+c)][n]
  {
    uint16_t* pb = po2 + ((size_t)(sp * 256 + b * 64 + hi * 4)) * NDIM + qrow;
#pragma unroll
    for (int r = 0; r < 16; r++) {
      const size_t off = (size_t)((r & 3) + 8 * (r >> 2)) * NDIM;
      pb[off] = f2bf(oacc0[r]);
      pb[off + (size_t)32 * NDIM] = f2bf(oacc1[r]);
    }
  }
  float ltot = (lacc[0] + lacc[1]) + (lacc[2] + lacc[3]);
  ltot += __shfl_xor(ltot, 32);
  if (hi == 0)
    ls[((size_t)sp * 4 + b) * NDIM + qrow] = ltot;
}

// ---------------- Kernel 3: split merge + gamma*O + residual ----------------
// 512 blocks x 256 threads; one thread = 8 consecutive n for one (b,c).
// All reads/writes fully coalesced along n; no LDS.
__global__ __launch_bounds__(256) void merge_kernel(
    const uint16_t* __restrict__ po2, const float* __restrict__ ls,
    const float* __restrict__ x_opt, const float* __restrict__ gamma,
    float* __restrict__ out)
{
  const int idx = blockIdx.x * 256 + threadIdx.x;   // 131072 threads
  const int n8 = (idx & 511) << 3;
  const int row = idx >> 9;              // b*64 + c
  const int b = row >> 6;

  float acc[8] = {0.f, 0.f, 0.f, 0.f, 0.f, 0.f, 0.f, 0.f};
  f32x4 ws0 = {0.f, 0.f, 0.f, 0.f};
  f32x4 ws1 = {0.f, 0.f, 0.f, 0.f};
#pragma unroll
  for (int s = 0; s < NSPLIT; s++) {
    const uint4 pv = *(const uint4*)(po2 + ((size_t)s * 256 + row) * NDIM + n8);
    const uint32_t* pw = (const uint32_t*)&pv;
#pragma unroll
    for (int j = 0; j < 4; j++) {
      acc[j * 2 + 0] += __uint_as_float(pw[j] << 16);
      acc[j * 2 + 1] += __uint_as_float(pw[j] & 0xFFFF0000u);
    }
    const float* lp = ls + ((size_t)s * 4 + b) * NDIM + n8;
    ws0 += *(const f32x4*)(lp);
    ws1 += *(const f32x4*)(lp + 4);
  }
  const float gm = gamma[0];
  const float* xp = x_opt + (size_t)row * NDIM + n8;
  float* op = out + (size_t)row * NDIM + n8;
  float4 x0 = ((const float4*)xp)[0];
  float4 x1 = ((const float4*)xp)[1];
  float4 o0, o1;
  o0.x = gm * acc[0] / ws0[0] + x0.x;
  o0.y = gm * acc[1] / ws0[1] + x0.y;
  o0.z = gm * acc[2] / ws0[2] + x0.z;
  o0.w = gm * acc[3] / ws0[3] + x0.w;
  o1.x = gm * acc[4] / ws1[0] + x1.x;
  o1.y = gm * acc[5] / ws1[1] + x1.y;
  o1.z = gm * acc[6] / ws1[2] + x1.z;
  o1.w = gm * acc[7] / ws1[3] + x1.w;
  ((float4*)op)[0] = o0;
  ((float4*)op)[1] = o1;
}

extern "C" void kernel_launch(void* const* d_in, const int* in_sizes, int n_in,
                              void* d_out, int out_size, void* d_ws, size_t ws_size,
                              hipStream_t stream) {
  const float* x_opt = (const float*)d_in[0];
  const float* x_sar = (const float*)d_in[1];
  const float* wq    = (const float*)d_in[2];
  const float* bq    = (const float*)d_in[3];
  const float* wk    = (const float*)d_in[4];
  const float* bk    = (const float*)d_in[5];
  const float* wvp   = (const float*)d_in[6];
  const float* bv    = (const float*)d_in[7];
  const float* gamma = (const float*)d_in[8];
  float* outp = (float*)d_out;

  // ws: qf 512K | kfp 256K(+256K pad) | vf2 2M | po2(bf16) 16M | ls 512K
  uint16_t* qf  = (uint16_t*)d_ws;
  uint16_t* kfp = (uint16_t*)((char*)d_ws + 524288);
  uint16_t* vf2 = (uint16_t*)((char*)d_ws + 1048576);
  uint16_t* po2 = (uint16_t*)((char*)d_ws + 3145728);
  float* lsp    = (float*)((char*)d_ws + 19922944);

  proj_kernel<<<512, 256, 0, stream>>>(x_opt, x_sar, wq, bq, wk, bk, wvp, bv,
                                       qf, kfp, vf2);
  attn_kernel<<<1024, 256, 0, stream>>>(qf, kfp, vf2, po2, lsp);
  merge_kernel<<<512, 256, 0, stream>>>(po2, lsp, x_opt, gamma, outp);
}